// Round 7
// baseline (125.756 us; speedup 1.0000x reference)
//
#include <hip/hip_runtime.h>
#include <stdint.h>

// ---------------------------------------------------------------------------
// VarianceMaximizationCovarianceMinimizationLoss on MI355X
//   features [65536,2,256] fp32, labels [65536] int32 -> scalar fp32 loss
// Round 7: round 6 + sched_barrier(0) pinning the cross-tile prefetch.
//   Theory: compiler sank the prefetched X loads to their first use after
//   the MFMA phase (VGPR=108 proves fa/fb not live across it), serializing
//   ~4 HBM latencies per tile. sched_barrier(0) after the load-issue block
//   makes the sink illegal; loads overlap the ds_read+MFMA phase.
// ---------------------------------------------------------------------------

#define NCLS  8
#define D     256
#define CHUNK 1024
#define SEG   256
#define EPSF  1e-4f
// sum_c ceil(n_c/CHUNK) <= nrows/CHUNK + NCLS-1 = 128+7 = 135
#define TMAX  144

typedef __bf16 bf16x8 __attribute__((ext_vector_type(8)));
typedef float  f32x4  __attribute__((ext_vector_type(4)));

__device__ __forceinline__ unsigned short f2bf(float f) {
    unsigned int x = __float_as_uint(f);
    x += 0x7fffu + ((x >> 16) & 1u);      // round-to-nearest-even
    return (unsigned short)(x >> 16);
}

// ---- k1a: histogram of row counts per class -------------------------------
__global__ void k_hist(const int* __restrict__ labels, int nlab, int vfac,
                       int* __restrict__ counts) {
    __shared__ int lc[NCLS];
    int t = threadIdx.x;
    if (t < NCLS) lc[t] = 0;
    __syncthreads();
    for (int i = blockIdx.x * blockDim.x + t; i < nlab; i += gridDim.x * blockDim.x)
        atomicAdd(&lc[labels[i] & 7], vfac);
    __syncthreads();
    if (t < NCLS && lc[t]) atomicAdd(&counts[t], lc[t]);
}

// ---- k1b: offsets + cursors ----------------------------------------------
__global__ void k_offsets(const int* __restrict__ counts,
                          int* __restrict__ offsets, int* __restrict__ cursor) {
    if (threadIdx.x == 0) {
        int acc = 0;
        for (int c = 0; c < NCLS; ++c) { offsets[c] = acc; cursor[c] = acc; acc += counts[c]; }
    }
}

// ---- k2: class-sorted row-index array -------------------------------------
__global__ __launch_bounds__(256) void k_idx(
    const int* __restrict__ labels, int nrows, int vfac,
    int* __restrict__ cursor, int* __restrict__ idx)
{
    __shared__ int lcnt[NCLS], lbase[NCLS];
    int t = threadIdx.x;
    int row = blockIdx.x * SEG + t;
    if (t < NCLS) lcnt[t] = 0;
    __syncthreads();
    int c = 0, rk = 0;
    bool ok = (row < nrows);
    if (ok) {
        c = labels[row / vfac] & 7;
        rk = atomicAdd(&lcnt[c], 1);
    }
    __syncthreads();
    if (t < NCLS) lbase[t] = lcnt[t] ? atomicAdd(&cursor[t], lcnt[t]) : 0;
    __syncthreads();
    if (ok) idx[lbase[c] + rk] = row;
}

// ---- k3: per-(chunk, col-half) Gram via MFMA, pinned pipelined gather -----
// WG = 512 threads, 8 waves as 4x2: wave computes 64 rows x 64 cols of the
// 256x128 output half. acc = 4x4 fragments = 64 regs/thread.
// LDS K-tile (64 k-rows x 256 feature-cols) stored transposed:
//   quad (ccol, k/4) at byte ccol*128 + ((k&~3)*2 ^ ((ccol&7)<<4))
// Staging thread (kblk=t&15, cblk=t>>4) owns k-rows kblk*4..+3, cols
// cblk*8..+7. Validated conflict-free (rounds 3-6: SQ_LDS_BANK_CONFLICT=0).
__global__ __launch_bounds__(512) void k_gram_g(
    const float* __restrict__ X, const int* __restrict__ idx,
    const int* __restrict__ counts, const int* __restrict__ offsets,
    float* __restrict__ part, float* __restrict__ csums)
{
    __shared__ __align__(16) unsigned char lds[64 * 256 * 2];   // 32 KB

    int t = threadIdx.x;
    int lane = t & 63;
    int w = t >> 6;
    int wrow = w >> 1;          // 0..3 : 64-row band
    int wcol = w & 1;           // 0..1 : 64-col band within the half
    int kblk = t & 15;
    int cblk = t >> 4;

    int nch[NCLS], ofch[NCLS];
    int T = 0;
    for (int c = 0; c < NCLS; ++c) {
        int n = counts[c];
        nch[c] = (n + CHUNK - 1) / CHUNK;
        ofch[c] = T;
        T += nch[c];
    }

    const f32x4 zf = {0.f, 0.f, 0.f, 0.f};

    for (int wk = blockIdx.x; wk < 2 * T; wk += gridDim.x) {
        int item = wk >> 1;
        int half = wk & 1;
        int c = 0;
        while (c < NCLS - 1 && item >= ofch[c + 1]) ++c;
        int chunk = item - ofch[c];
        int base = offsets[c] + chunk * CHUNK;
        int rows = min(CHUNK, counts[c] - chunk * CHUNK);
        int ntiles = (rows + 63) >> 6;

        f32x4 acc[4][4];
        #pragma unroll
        for (int i = 0; i < 4; ++i)
            #pragma unroll
            for (int j = 0; j < 4; ++j)
                #pragma unroll
                for (int r = 0; r < 4; ++r) acc[i][j][r] = 0.f;
        float sumv[8];
        #pragma unroll
        for (int q = 0; q < 8; ++q) sumv[q] = 0.f;

        uint4 R[4];        // packed bf16, current tile (4 rows x 8 cols/thread)
        f32x4 fa[4], fb[4];
        int idn[4];        // row ids for the NEXT tile to issue

        // ---- prologue: tile-0 ids -> X loads -> tile-1 ids -> convert -----
        #pragma unroll
        for (int j = 0; j < 4; ++j) {
            int r = kblk * 4 + j;
            idn[j] = (r < rows) ? idx[base + r] : 0;
        }
        #pragma unroll
        for (int j = 0; j < 4; ++j) {
            int r = kblk * 4 + j;
            if (r < rows) {
                const float* rp = X + ((size_t)idn[j] << 8) + cblk * 8;
                fa[j] = *(const f32x4*)rp;
                fb[j] = *(const f32x4*)(rp + 4);
            } else { fa[j] = zf; fb[j] = zf; }
        }
        #pragma unroll
        for (int j = 0; j < 4; ++j) {
            int r = 64 + kblk * 4 + j;
            idn[j] = (r < rows) ? idx[base + r] : 0;
        }
        #pragma unroll
        for (int j = 0; j < 4; ++j) {
            #pragma unroll
            for (int q = 0; q < 4; ++q) { sumv[q] += fa[j][q]; sumv[4 + q] += fb[j][q]; }
            unsigned int w0 = (unsigned int)f2bf(fa[j][0]) | ((unsigned int)f2bf(fa[j][1]) << 16);
            unsigned int w1 = (unsigned int)f2bf(fa[j][2]) | ((unsigned int)f2bf(fa[j][3]) << 16);
            unsigned int w2 = (unsigned int)f2bf(fb[j][0]) | ((unsigned int)f2bf(fb[j][1]) << 16);
            unsigned int w3 = (unsigned int)f2bf(fb[j][2]) | ((unsigned int)f2bf(fb[j][3]) << 16);
            R[j] = make_uint4(w0, w1, w2, w3);
        }

        for (int kt = 0; kt < ntiles; ++kt) {
            __syncthreads();           // previous tile's LDS reads done
            // R -> LDS transposed (4 k-rows packed per 8B write)
            #pragma unroll
            for (int cc = 0; cc < 8; ++cc) {
                int wd = cc >> 1;
                int sh = (cc & 1) * 16;
                unsigned int e0 = (((const unsigned int*)&R[0])[wd] >> sh) & 0xffffu;
                unsigned int e1 = (((const unsigned int*)&R[1])[wd] >> sh) & 0xffffu;
                unsigned int e2 = (((const unsigned int*)&R[2])[wd] >> sh) & 0xffffu;
                unsigned int e3 = (((const unsigned int*)&R[3])[wd] >> sh) & 0xffffu;
                int ccol = cblk * 8 + cc;
                int byt = ccol * 128 + ((kblk * 8) ^ (cc << 4));
                *(uint2*)(lds + byt) = make_uint2(e0 | (e1 << 16), e2 | (e3 << 16));
            }
            __syncthreads();           // staging visible

            // issue NEXT tile's X loads; sched_barrier(0) below makes it
            // ILLEGAL for the scheduler to sink them into/past the MFMA
            // phase (round-6 failure mode: VGPR=108 proved they sank)
            bool more = (kt + 1 < ntiles);
            if (more) {
                #pragma unroll
                for (int j = 0; j < 4; ++j) {
                    int r = (kt + 1) * 64 + kblk * 4 + j;
                    if (r < rows) {
                        const float* rp = X + ((size_t)idn[j] << 8) + cblk * 8;
                        fa[j] = *(const f32x4*)rp;
                        fb[j] = *(const f32x4*)(rp + 4);
                    } else { fa[j] = zf; fb[j] = zf; }
                }
            }
            // ids for tile kt+2 (L2-resident, consumed next iteration)
            int idf[4];
            #pragma unroll
            for (int j = 0; j < 4; ++j) {
                int r = (kt + 2) * 64 + kblk * 4 + j;
                idf[j] = (more && r < rows) ? idx[base + r] : 0;
            }
            __builtin_amdgcn_sched_barrier(0);   // pin loads above MFMA phase

            // MFMA: 2 k-steps of 32; af loaded per-ti (transient)
            #pragma unroll
            for (int ks = 0; ks < 2; ++ks) {
                int kb2 = ks * 64 + ((lane >> 4) << 4);
                int swz = (lane & 7) << 4;
                bf16x8 bfr[4];
                #pragma unroll
                for (int tj = 0; tj < 4; ++tj) {
                    int ccol = half * 128 + wcol * 64 + tj * 16 + (lane & 15);
                    bfr[tj] = __builtin_bit_cast(bf16x8,
                        *(const uint4*)(lds + ccol * 128 + (kb2 ^ swz)));
                }
                #pragma unroll
                for (int ti = 0; ti < 4; ++ti) {
                    int ccol = wrow * 64 + ti * 16 + (lane & 15);
                    bf16x8 af = __builtin_bit_cast(bf16x8,
                        *(const uint4*)(lds + ccol * 128 + (kb2 ^ swz)));
                    #pragma unroll
                    for (int tj = 0; tj < 4; ++tj)
                        acc[ti][tj] = __builtin_amdgcn_mfma_f32_16x16x32_bf16(
                            af, bfr[tj], acc[ti][tj], 0, 0, 0);
                }
            }

            // convert next tile (first consume of the in-flight loads) + sums
            if (more) {
                #pragma unroll
                for (int j = 0; j < 4; ++j) {
                    #pragma unroll
                    for (int q = 0; q < 4; ++q) { sumv[q] += fa[j][q]; sumv[4 + q] += fb[j][q]; }
                    unsigned int w0 = (unsigned int)f2bf(fa[j][0]) | ((unsigned int)f2bf(fa[j][1]) << 16);
                    unsigned int w1 = (unsigned int)f2bf(fa[j][2]) | ((unsigned int)f2bf(fa[j][3]) << 16);
                    unsigned int w2 = (unsigned int)f2bf(fb[j][0]) | ((unsigned int)f2bf(fb[j][1]) << 16);
                    unsigned int w3 = (unsigned int)f2bf(fb[j][2]) | ((unsigned int)f2bf(fb[j][3]) << 16);
                    R[j] = make_uint4(w0, w1, w2, w3);
                }
                #pragma unroll
                for (int j = 0; j < 4; ++j) idn[j] = idf[j];
            }
        }

        // flush: plain stores (C/D: col=lane&15, row=(lane>>4)*4+r)
        float* dst = part + (size_t)item * (D * D);
        #pragma unroll
        for (int ti = 0; ti < 4; ++ti) {
            int row0 = wrow * 64 + ti * 16 + ((lane >> 4) << 2);
            #pragma unroll
            for (int tj = 0; tj < 4; ++tj) {
                int col = half * 128 + wcol * 64 + tj * 16 + (lane & 15);
                #pragma unroll
                for (int r = 0; r < 4; ++r)
                    dst[(row0 + r) * D + col] = acc[ti][tj][r];
            }
        }

        // per-chunk column sums (both halves compute; half 0 writes)
        #pragma unroll
        for (int s = 1; s < 16; s <<= 1)
            #pragma unroll
            for (int q = 0; q < 8; ++q)
                sumv[q] += __shfl_xor(sumv[q], s, 64);
        if (half == 0 && (t & 15) == 0) {
            float* cs = csums + (size_t)item * D + cblk * 8;
            #pragma unroll
            for (int q = 0; q < 8; ++q) cs[q] = sumv[q];
        }
        __syncthreads();   // protect LDS before next work-item's staging
    }
}

// ---- k4: reduce per-chunk column sums -> per-class sums -------------------
__global__ __launch_bounds__(256) void k_gsum(
    const float* __restrict__ csums, const int* __restrict__ counts,
    float* __restrict__ gsums)
{
    int c = blockIdx.x;
    int i = threadIdx.x;
    int of = 0;
    for (int cc = 0; cc < c; ++cc) of += (counts[cc] + CHUNK - 1) / CHUNK;
    int nc = (counts[c] + CHUNK - 1) / CHUNK;
    float s = 0.f;
    for (int q = 0; q < nc; ++q) s += csums[(size_t)(of + q) * D + i];
    gsums[c * D + i] = s;
}

// ---- k5: loss epilogue from per-chunk partial Grams -----------------------
__global__ __launch_bounds__(256) void k_loss(
    const float* __restrict__ part, const float* __restrict__ gsums,
    const int* __restrict__ counts, float* __restrict__ out)
{
    __shared__ float red[256];
    int t = threadIdx.x;
    int nch[NCLS], ofch[NCLS];
    int T = 0;
    for (int c = 0; c < NCLS; ++c) {
        int n = counts[c];
        nch[c] = (n + CHUNK - 1) / CHUNK;
        ofch[c] = T;
        T += nch[c];
    }
    float local = 0.f;
    const int total = NCLS * D * D;
    for (int idx = blockIdx.x * blockDim.x + t; idx < total; idx += gridDim.x * blockDim.x) {
        int c = idx >> 16;
        int ij = idx & 0xffff;
        int i = ij >> 8, j = ij & 255;
        const float* p = part + (size_t)ofch[c] * (D * D) + ij;
        float s = 0.f;
        for (int q = 0; q < nch[c]; ++q) s += p[(size_t)q * (D * D)];
        float n  = (float)counts[c];
        float mi = gsums[c * D + i] / n;
        float mj = gsums[c * D + j] / n;
        float cov = (s - n * mi * mj) / (n - 1.f);
        float contrib;
        if (i == j) {
            float sd = sqrtf(cov + EPSF);
            contrib = fmaxf(1.f - sd, 0.f) * (1.f / (float)D);
        } else {
            contrib = cov * cov * (1.f / (float)D);
        }
        local += contrib;
    }
    red[t] = local;
    __syncthreads();
    for (int s = 128; s > 0; s >>= 1) {
        if (t < s) red[t] += red[t + s];
        __syncthreads();
    }
    if (t == 0) atomicAdd(out, red[0]);
}

// ---------------------------------------------------------------------------
extern "C" void kernel_launch(void* const* d_in, const int* in_sizes, int n_in,
                              void* d_out, int out_size, void* d_ws, size_t ws_size,
                              hipStream_t stream)
{
    const float* X      = (const float*)d_in[0];
    const int*   labels = (const int*)d_in[1];
    int nfeat = in_sizes[0];
    int nlab  = in_sizes[1];
    int nrows = nfeat / D;            // 131072
    int vfac  = nrows / nlab;         // 2 views per sample

    char* ws = (char*)d_ws;
    size_t off_idx   = 0;
    size_t sz_idx    = (size_t)nrows * 4;                 // 512 KB
    size_t off_part  = (off_idx + sz_idx + 255) & ~(size_t)255;
    size_t sz_part   = (size_t)TMAX * D * D * 4;          // 37.7 MB
    size_t off_cs    = (off_part + sz_part + 255) & ~(size_t)255;
    size_t sz_cs     = (size_t)TMAX * D * 4;              // 147 KB
    size_t off_gs    = (off_cs + sz_cs + 255) & ~(size_t)255;
    size_t sz_gs     = (size_t)NCLS * D * 4;              // 8 KB
    size_t off_cnt   = (off_gs + sz_gs + 255) & ~(size_t)255;
    size_t off_ofs   = off_cnt + 64;
    size_t off_cur   = off_ofs + 64;

    int*   idx     = (int*)(ws + off_idx);
    float* part    = (float*)(ws + off_part);
    float* csums   = (float*)(ws + off_cs);
    float* gsums   = (float*)(ws + off_gs);
    int*   counts  = (int*)(ws + off_cnt);
    int*   offsets = (int*)(ws + off_ofs);
    int*   cursor  = (int*)(ws + off_cur);

    hipMemsetAsync(counts, 0, 64, stream);
    hipMemsetAsync(d_out, 0, (size_t)out_size * sizeof(float), stream);

    k_hist<<<64, 256, 0, stream>>>(labels, nlab, vfac, counts);
    k_offsets<<<1, 64, 0, stream>>>(counts, offsets, cursor);
    k_idx<<<(nrows + SEG - 1) / SEG, SEG, 0, stream>>>(labels, nrows, vfac, cursor, idx);
    k_gram_g<<<2 * TMAX, 512, 0, stream>>>(X, idx, counts, offsets, part, csums);
    k_gsum<<<NCLS, 256, 0, stream>>>(csums, counts, gsums);
    k_loss<<<512, 256, 0, stream>>>(part, gsums, counts, (float*)d_out);
}

// Round 8
// 115.518 us; speedup vs baseline: 1.0886x; 1.0886x over previous
//
#include <hip/hip_runtime.h>
#include <stdint.h>

// ---------------------------------------------------------------------------
// VarianceMaximizationCovarianceMinimizationLoss on MI355X
//   features [65536,2,256] fp32, labels [65536] int32 -> scalar fp32 loss
// Round 8: branch-free software pipeline + double-buffered LDS.
//   Rounds 6/7 failed because the conditional prefetch (if(more){loads}) and
//   its conditional consume were CFG-merged by the compiler, re-serializing
//   the per-tile HBM latency. This version peels the loop so the prefetch is
//   unconditional straight-line code; sched_barrier(0) fences pin
//   issue -> MFMA -> consume order; 2x32KB LDS buffers, one barrier/tile.
// ---------------------------------------------------------------------------

#define NCLS  8
#define D     256
#define CHUNK 1024
#define SEG   256
#define EPSF  1e-4f
// sum_c ceil(n_c/CHUNK) <= nrows/CHUNK + NCLS-1 = 128+7 = 135
#define TMAX  144

typedef __bf16 bf16x8 __attribute__((ext_vector_type(8)));
typedef float  f32x4  __attribute__((ext_vector_type(4)));

__device__ __forceinline__ unsigned short f2bf(float f) {
    unsigned int x = __float_as_uint(f);
    x += 0x7fffu + ((x >> 16) & 1u);      // round-to-nearest-even
    return (unsigned short)(x >> 16);
}

// ---- k1a: histogram of row counts per class -------------------------------
__global__ void k_hist(const int* __restrict__ labels, int nlab, int vfac,
                       int* __restrict__ counts) {
    __shared__ int lc[NCLS];
    int t = threadIdx.x;
    if (t < NCLS) lc[t] = 0;
    __syncthreads();
    for (int i = blockIdx.x * blockDim.x + t; i < nlab; i += gridDim.x * blockDim.x)
        atomicAdd(&lc[labels[i] & 7], vfac);
    __syncthreads();
    if (t < NCLS && lc[t]) atomicAdd(&counts[t], lc[t]);
}

// ---- k1b: offsets + cursors ----------------------------------------------
__global__ void k_offsets(const int* __restrict__ counts,
                          int* __restrict__ offsets, int* __restrict__ cursor) {
    if (threadIdx.x == 0) {
        int acc = 0;
        for (int c = 0; c < NCLS; ++c) { offsets[c] = acc; cursor[c] = acc; acc += counts[c]; }
    }
}

// ---- k2: class-sorted row-index array -------------------------------------
__global__ __launch_bounds__(256) void k_idx(
    const int* __restrict__ labels, int nrows, int vfac,
    int* __restrict__ cursor, int* __restrict__ idx)
{
    __shared__ int lcnt[NCLS], lbase[NCLS];
    int t = threadIdx.x;
    int row = blockIdx.x * SEG + t;
    if (t < NCLS) lcnt[t] = 0;
    __syncthreads();
    int c = 0, rk = 0;
    bool ok = (row < nrows);
    if (ok) {
        c = labels[row / vfac] & 7;
        rk = atomicAdd(&lcnt[c], 1);
    }
    __syncthreads();
    if (t < NCLS) lbase[t] = lcnt[t] ? atomicAdd(&cursor[t], lcnt[t]) : 0;
    __syncthreads();
    if (ok) idx[lbase[c] + rk] = row;
}

// ---- k3: per-(chunk, col-half) Gram, branch-free pipelined gather ---------
// WG = 512 threads, 8 waves as 4x2: wave computes 64 rows x 64 cols of the
// 256x128 output half. acc = 4x4 fragments = 64 regs/thread.
// LDS K-tile (64 k-rows x 256 feature-cols), double-buffered, transposed:
//   quad (ccol, k/4) at byte buf*32768 + ccol*128 + ((k&~3)*2 ^ ((ccol&7)<<4))
// Staging thread (kblk=t&15, cblk=t>>4) owns k-rows kblk*4..+3, cols
// cblk*8..+7. Validated conflict-free (rounds 3-7: SQ_LDS_BANK_CONFLICT=0).
__global__ __launch_bounds__(512) void k_gram_g(
    const float* __restrict__ X, const int* __restrict__ idx,
    const int* __restrict__ counts, const int* __restrict__ offsets,
    float* __restrict__ part, float* __restrict__ csums)
{
    __shared__ __align__(16) unsigned char lds[2][64 * 256 * 2];   // 64 KB

    int t = threadIdx.x;
    int lane = t & 63;
    int w = t >> 6;
    int wrow = w >> 1;          // 0..3 : 64-row band
    int wcol = w & 1;           // 0..1 : 64-col band within the half
    int kblk = t & 15;
    int cblk = t >> 4;

    int nch[NCLS], ofch[NCLS];
    int T = 0;
    for (int c = 0; c < NCLS; ++c) {
        int n = counts[c];
        nch[c] = (n + CHUNK - 1) / CHUNK;
        ofch[c] = T;
        T += nch[c];
    }

    const f32x4 zf = {0.f, 0.f, 0.f, 0.f};

    for (int wk = blockIdx.x; wk < 2 * T; wk += gridDim.x) {
        int item = wk >> 1;
        int half = wk & 1;
        int c = 0;
        while (c < NCLS - 1 && item >= ofch[c + 1]) ++c;
        int chunk = item - ofch[c];
        int base = offsets[c] + chunk * CHUNK;
        int rows = min(CHUNK, counts[c] - chunk * CHUNK);
        int ntiles = (rows + 63) >> 6;

        f32x4 acc[4][4];
        #pragma unroll
        for (int i = 0; i < 4; ++i)
            #pragma unroll
            for (int j = 0; j < 4; ++j)
                #pragma unroll
                for (int r = 0; r < 4; ++r) acc[i][j][r] = 0.f;
        float sumv[8];
        #pragma unroll
        for (int q = 0; q < 8; ++q) sumv[q] = 0.f;

        f32x4 fa[4], fb[4];
        uint4 R[4];
        int idn[4];

        // ================= prologue: stage tile 0 into buf0 =================
        #pragma unroll
        for (int j = 0; j < 4; ++j) {
            int r = kblk * 4 + j;
            int rid = idx[base + min(r, rows - 1)];
            const float* rp = X + ((size_t)rid << 8) + cblk * 8;
            fa[j] = *(const f32x4*)rp;
            fb[j] = *(const f32x4*)(rp + 4);
            if (r >= rows) { fa[j] = zf; fb[j] = zf; }
        }
        #pragma unroll
        for (int j = 0; j < 4; ++j) {
            int r = 64 + kblk * 4 + j;
            idn[j] = idx[base + min(r, rows - 1)];
        }
        #pragma unroll
        for (int j = 0; j < 4; ++j) {
            #pragma unroll
            for (int q = 0; q < 4; ++q) { sumv[q] += fa[j][q]; sumv[4 + q] += fb[j][q]; }
            unsigned int w0 = (unsigned int)f2bf(fa[j][0]) | ((unsigned int)f2bf(fa[j][1]) << 16);
            unsigned int w1 = (unsigned int)f2bf(fa[j][2]) | ((unsigned int)f2bf(fa[j][3]) << 16);
            unsigned int w2 = (unsigned int)f2bf(fb[j][0]) | ((unsigned int)f2bf(fb[j][1]) << 16);
            unsigned int w3 = (unsigned int)f2bf(fb[j][2]) | ((unsigned int)f2bf(fb[j][3]) << 16);
            R[j] = make_uint4(w0, w1, w2, w3);
        }
        #pragma unroll
        for (int cc = 0; cc < 8; ++cc) {
            int wd = cc >> 1;
            int sh = (cc & 1) * 16;
            unsigned int e0 = (((const unsigned int*)&R[0])[wd] >> sh) & 0xffffu;
            unsigned int e1 = (((const unsigned int*)&R[1])[wd] >> sh) & 0xffffu;
            unsigned int e2 = (((const unsigned int*)&R[2])[wd] >> sh) & 0xffffu;
            unsigned int e3 = (((const unsigned int*)&R[3])[wd] >> sh) & 0xffffu;
            int ccol = cblk * 8 + cc;
            int byt = ccol * 128 + ((kblk * 8) ^ (cc << 4));
            *(uint2*)(&lds[0][0] + byt) = make_uint2(e0 | (e1 << 16), e2 | (e3 << 16));
        }
        __syncthreads();

        // ================= main loop: branch-free A/B/C pipeline ============
        int ntm1 = ntiles - 1;
        for (int kt = 0; kt < ntm1; ++kt) {
            int cur = kt & 1;
            // --- A: issue tile kt+1 loads (unconditional, clamped ids) ---
            #pragma unroll
            for (int j = 0; j < 4; ++j) {
                const float* rp = X + ((size_t)idn[j] << 8) + cblk * 8;
                fa[j] = *(const f32x4*)rp;
                fb[j] = *(const f32x4*)(rp + 4);
            }
            int idnn[4];
            #pragma unroll
            for (int j = 0; j < 4; ++j) {
                int r = (kt + 2) * 64 + kblk * 4 + j;
                idnn[j] = idx[base + min(r, rows - 1)];
            }
            __builtin_amdgcn_sched_barrier(0);   // loads must issue before MFMA

            // --- B: MFMA on buf[cur] ---
            {
                const unsigned char* lb = &lds[0][0] + cur * 32768;
                #pragma unroll
                for (int ks = 0; ks < 2; ++ks) {
                    int kb2 = ks * 64 + ((lane >> 4) << 4);
                    int swz = (lane & 7) << 4;
                    bf16x8 bfr[4];
                    #pragma unroll
                    for (int tj = 0; tj < 4; ++tj) {
                        int ccol = half * 128 + wcol * 64 + tj * 16 + (lane & 15);
                        bfr[tj] = __builtin_bit_cast(bf16x8,
                            *(const uint4*)(lb + ccol * 128 + (kb2 ^ swz)));
                    }
                    #pragma unroll
                    for (int ti = 0; ti < 4; ++ti) {
                        int ccol = wrow * 64 + ti * 16 + (lane & 15);
                        bf16x8 af = __builtin_bit_cast(bf16x8,
                            *(const uint4*)(lb + ccol * 128 + (kb2 ^ swz)));
                        #pragma unroll
                        for (int tj = 0; tj < 4; ++tj)
                            acc[ti][tj] = __builtin_amdgcn_mfma_f32_16x16x32_bf16(
                                af, bfr[tj], acc[ti][tj], 0, 0, 0);
                    }
                }
            }
            __builtin_amdgcn_sched_barrier(0);   // consume stays after MFMA

            // --- C: zero-select + sums + pack + ds_write buf[cur^1] ---
            #pragma unroll
            for (int j = 0; j < 4; ++j) {
                int r = (kt + 1) * 64 + kblk * 4 + j;
                if (r >= rows) { fa[j] = zf; fb[j] = zf; }
                #pragma unroll
                for (int q = 0; q < 4; ++q) { sumv[q] += fa[j][q]; sumv[4 + q] += fb[j][q]; }
                unsigned int w0 = (unsigned int)f2bf(fa[j][0]) | ((unsigned int)f2bf(fa[j][1]) << 16);
                unsigned int w1 = (unsigned int)f2bf(fa[j][2]) | ((unsigned int)f2bf(fa[j][3]) << 16);
                unsigned int w2 = (unsigned int)f2bf(fb[j][0]) | ((unsigned int)f2bf(fb[j][1]) << 16);
                unsigned int w3 = (unsigned int)f2bf(fb[j][2]) | ((unsigned int)f2bf(fb[j][3]) << 16);
                R[j] = make_uint4(w0, w1, w2, w3);
            }
            {
                unsigned char* wb = &lds[0][0] + (cur ^ 1) * 32768;
                #pragma unroll
                for (int cc = 0; cc < 8; ++cc) {
                    int wd = cc >> 1;
                    int sh = (cc & 1) * 16;
                    unsigned int e0 = (((const unsigned int*)&R[0])[wd] >> sh) & 0xffffu;
                    unsigned int e1 = (((const unsigned int*)&R[1])[wd] >> sh) & 0xffffu;
                    unsigned int e2 = (((const unsigned int*)&R[2])[wd] >> sh) & 0xffffu;
                    unsigned int e3 = (((const unsigned int*)&R[3])[wd] >> sh) & 0xffffu;
                    int ccol = cblk * 8 + cc;
                    int byt = ccol * 128 + ((kblk * 8) ^ (cc << 4));
                    *(uint2*)(wb + byt) = make_uint2(e0 | (e1 << 16), e2 | (e3 << 16));
                }
            }
            #pragma unroll
            for (int j = 0; j < 4; ++j) idn[j] = idnn[j];
            __syncthreads();
        }

        // ================= epilogue: MFMA last tile =========================
        {
            const unsigned char* lb = &lds[0][0] + (ntm1 & 1) * 32768;
            #pragma unroll
            for (int ks = 0; ks < 2; ++ks) {
                int kb2 = ks * 64 + ((lane >> 4) << 4);
                int swz = (lane & 7) << 4;
                bf16x8 bfr[4];
                #pragma unroll
                for (int tj = 0; tj < 4; ++tj) {
                    int ccol = half * 128 + wcol * 64 + tj * 16 + (lane & 15);
                    bfr[tj] = __builtin_bit_cast(bf16x8,
                        *(const uint4*)(lb + ccol * 128 + (kb2 ^ swz)));
                }
                #pragma unroll
                for (int ti = 0; ti < 4; ++ti) {
                    int ccol = wrow * 64 + ti * 16 + (lane & 15);
                    bf16x8 af = __builtin_bit_cast(bf16x8,
                        *(const uint4*)(lb + ccol * 128 + (kb2 ^ swz)));
                    #pragma unroll
                    for (int tj = 0; tj < 4; ++tj)
                        acc[ti][tj] = __builtin_amdgcn_mfma_f32_16x16x32_bf16(
                            af, bfr[tj], acc[ti][tj], 0, 0, 0);
                }
            }
        }

        // flush: plain stores (C/D: col=lane&15, row=(lane>>4)*4+r)
        float* dst = part + (size_t)item * (D * D);
        #pragma unroll
        for (int ti = 0; ti < 4; ++ti) {
            int row0 = wrow * 64 + ti * 16 + ((lane >> 4) << 2);
            #pragma unroll
            for (int tj = 0; tj < 4; ++tj) {
                int col = half * 128 + wcol * 64 + tj * 16 + (lane & 15);
                #pragma unroll
                for (int r = 0; r < 4; ++r)
                    dst[(row0 + r) * D + col] = acc[ti][tj][r];
            }
        }

        // per-chunk column sums (both halves compute; half 0 writes)
        #pragma unroll
        for (int s = 1; s < 16; s <<= 1)
            #pragma unroll
            for (int q = 0; q < 8; ++q)
                sumv[q] += __shfl_xor(sumv[q], s, 64);
        if (half == 0 && (t & 15) == 0) {
            float* cs = csums + (size_t)item * D + cblk * 8;
            #pragma unroll
            for (int q = 0; q < 8; ++q) cs[q] = sumv[q];
        }
        __syncthreads();   // protect LDS before next work-item's prologue
    }
}

// ---- k4: reduce per-chunk column sums -> per-class sums -------------------
__global__ __launch_bounds__(256) void k_gsum(
    const float* __restrict__ csums, const int* __restrict__ counts,
    float* __restrict__ gsums)
{
    int c = blockIdx.x;
    int i = threadIdx.x;
    int of = 0;
    for (int cc = 0; cc < c; ++cc) of += (counts[cc] + CHUNK - 1) / CHUNK;
    int nc = (counts[c] + CHUNK - 1) / CHUNK;
    float s = 0.f;
    for (int q = 0; q < nc; ++q) s += csums[(size_t)(of + q) * D + i];
    gsums[c * D + i] = s;
}

// ---- k5: loss epilogue from per-chunk partial Grams -----------------------
__global__ __launch_bounds__(256) void k_loss(
    const float* __restrict__ part, const float* __restrict__ gsums,
    const int* __restrict__ counts, float* __restrict__ out)
{
    __shared__ float red[256];
    int t = threadIdx.x;
    int nch[NCLS], ofch[NCLS];
    int T = 0;
    for (int c = 0; c < NCLS; ++c) {
        int n = counts[c];
        nch[c] = (n + CHUNK - 1) / CHUNK;
        ofch[c] = T;
        T += nch[c];
    }
    float local = 0.f;
    const int total = NCLS * D * D;
    for (int idx = blockIdx.x * blockDim.x + t; idx < total; idx += gridDim.x * blockDim.x) {
        int c = idx >> 16;
        int ij = idx & 0xffff;
        int i = ij >> 8, j = ij & 255;
        const float* p = part + (size_t)ofch[c] * (D * D) + ij;
        float s = 0.f;
        for (int q = 0; q < nch[c]; ++q) s += p[(size_t)q * (D * D)];
        float n  = (float)counts[c];
        float mi = gsums[c * D + i] / n;
        float mj = gsums[c * D + j] / n;
        float cov = (s - n * mi * mj) / (n - 1.f);
        float contrib;
        if (i == j) {
            float sd = sqrtf(cov + EPSF);
            contrib = fmaxf(1.f - sd, 0.f) * (1.f / (float)D);
        } else {
            contrib = cov * cov * (1.f / (float)D);
        }
        local += contrib;
    }
    red[t] = local;
    __syncthreads();
    for (int s = 128; s > 0; s >>= 1) {
        if (t < s) red[t] += red[t + s];
        __syncthreads();
    }
    if (t == 0) atomicAdd(out, red[0]);
}

// ---------------------------------------------------------------------------
extern "C" void kernel_launch(void* const* d_in, const int* in_sizes, int n_in,
                              void* d_out, int out_size, void* d_ws, size_t ws_size,
                              hipStream_t stream)
{
    const float* X      = (const float*)d_in[0];
    const int*   labels = (const int*)d_in[1];
    int nfeat = in_sizes[0];
    int nlab  = in_sizes[1];
    int nrows = nfeat / D;            // 131072
    int vfac  = nrows / nlab;         // 2 views per sample

    char* ws = (char*)d_ws;
    size_t off_idx   = 0;
    size_t sz_idx    = (size_t)nrows * 4;                 // 512 KB
    size_t off_part  = (off_idx + sz_idx + 255) & ~(size_t)255;
    size_t sz_part   = (size_t)TMAX * D * D * 4;          // 37.7 MB
    size_t off_cs    = (off_part + sz_part + 255) & ~(size_t)255;
    size_t sz_cs     = (size_t)TMAX * D * 4;              // 147 KB
    size_t off_gs    = (off_cs + sz_cs + 255) & ~(size_t)255;
    size_t sz_gs     = (size_t)NCLS * D * 4;              // 8 KB
    size_t off_cnt   = (off_gs + sz_gs + 255) & ~(size_t)255;
    size_t off_ofs   = off_cnt + 64;
    size_t off_cur   = off_ofs + 64;

    int*   idx     = (int*)(ws + off_idx);
    float* part    = (float*)(ws + off_part);
    float* csums   = (float*)(ws + off_cs);
    float* gsums   = (float*)(ws + off_gs);
    int*   counts  = (int*)(ws + off_cnt);
    int*   offsets = (int*)(ws + off_ofs);
    int*   cursor  = (int*)(ws + off_cur);

    hipMemsetAsync(counts, 0, 64, stream);
    hipMemsetAsync(d_out, 0, (size_t)out_size * sizeof(float), stream);

    k_hist<<<64, 256, 0, stream>>>(labels, nlab, vfac, counts);
    k_offsets<<<1, 64, 0, stream>>>(counts, offsets, cursor);
    k_idx<<<(nrows + SEG - 1) / SEG, SEG, 0, stream>>>(labels, nrows, vfac, cursor, idx);
    k_gram_g<<<2 * TMAX, 512, 0, stream>>>(X, idx, counts, offsets, part, csums);
    k_gsum<<<NCLS, 256, 0, stream>>>(csums, counts, gsums);
    k_loss<<<512, 256, 0, stream>>>(part, gsums, counts, (float*)d_out);
}